// Round 5
// baseline (30838.904 us; speedup 1.0000x reference)
//
#include <hip/hip_runtime.h>

// NeuralODE SIREN (2->128->128->2, sin, w0=44), RK4 3/8-rule, 100 steps.
// Round 7: pure compute-bound now (WRITE=213MB ideal, FETCH~0). MfmaUtil 39.6%
// == 10.3 TFLOP / 2075 TF / 12.3ms exactly -> MFMA floor ~5ms; gap is VALU
// issue (66% busy) + A-build<->MFMA serialization within each wave.
//  - fract DROPPED: weights prescaled to revolutions, |z| <= ~55 << v_sin's
//    +-256 valid domain. -256 VALU inst/f-eval, shorter sin chain.
//  - A hi/lo via TRUNCATION split + v_perm packing: ah = top16 bits (pair
//    packed by ONE v_perm), al = top16 of exact residual (ONE v_perm). 24
//    inst per 4 values vs ~35. Residual ~2^-15.4 (was 2^-16.3): absmax may
//    rise ~2x, still ~3x under threshold.
//  - c-loop SOFTWARE-PIPELINED (full unroll, parity double-buffered A-frags):
//    build A(c+1) overlaps the 96-MFMA sweep of c within the same wave.
//    +16 VGPRs (~235 unified peak <= 256; WRITE_SIZE is the spill canary).

#define W0F    44.0f
#define INV2PI 0.15915494309189535f
#define SCALE  (W0F * INV2PI)
#define WIDTH  128
#define NPART  262144
#define TSTEPS 101

typedef short s16x8 __attribute__((ext_vector_type(8)));
typedef float f32x4 __attribute__((ext_vector_type(4)));

__device__ __forceinline__ float sin_rev(float z) {
    // sin(2*pi*z) via v_sin_f32 (revolutions). Valid domain +-256 rev;
    // |z| <= ~55 here (|x|<=7, |W1|<=0.5, SCALE=7.005). No fract needed.
    return __builtin_amdgcn_sinf(z);
}
__device__ __forceinline__ unsigned short f2bf(float x) {   // RNE f32->bf16
    __bf16 b = (__bf16)x;
    return __builtin_bit_cast(unsigned short, b);
}
__device__ __forceinline__ float bf2f(unsigned short u) {   // exact bf16->f32
    unsigned int v = ((unsigned int)u) << 16;
    return __builtin_bit_cast(float, v);
}
__device__ __forceinline__ float trunc16f(float v) {        // f32 with low 16 mantissa bits cleared
    return __builtin_bit_cast(float, __builtin_bit_cast(unsigned int, v) & 0xffff0000u);
}
__device__ __forceinline__ unsigned int pack_hi16(float vlo, float vhi) {
    // {top16(vhi) : top16(vlo)} in one v_perm_b32 (vlo's top half -> low 16)
    return __builtin_amdgcn_perm(__builtin_bit_cast(unsigned int, vhi),
                                 __builtin_bit_cast(unsigned int, vlo),
                                 0x07060302u);
}

// ---- 16-lane (DPP row) all-lanes sum via circulant row_ror adds ----
#define ROR_ADD(x, ctrl) ((x) + __builtin_bit_cast(float, \
    __builtin_amdgcn_update_dpp(0, __builtin_bit_cast(int, (x)), (ctrl), 0xF, 0xF, false)))
__device__ __forceinline__ float row_sum16(float x) {
    x = ROR_ADD(x, 0x128);   // row_ror:8
    x = ROR_ADD(x, 0x124);   // row_ror:4
    x = ROR_ADD(x, 0x122);   // row_ror:2
    x = ROR_ADD(x, 0x121);   // row_ror:1
    return x;                // every lane holds the 16-lane sum
}

// 16-way register select (15 v_cndmask), idx = per-lane 0..15
__device__ __forceinline__ float sel16(const float g[16], int idx) {
    float a[8], b[4], c[2];
    #pragma unroll
    for (int i = 0; i < 8; ++i) a[i] = (idx & 8) ? g[i + 8] : g[i];
    #pragma unroll
    for (int i = 0; i < 4; ++i) b[i] = (idx & 4) ? a[i + 4] : a[i];
    #pragma unroll
    for (int i = 0; i < 2; ++i) c[i] = (idx & 2) ? b[i + 2] : b[i];
    return (idx & 1) ? c[1] : c[0];
}

// ws layout: shorts [0,16384) = W2-hi B-frags; shorts [16384,32768) = W2-lo
// B-frags; floats [16384,16640) = SCALE*W1; floats [16640,16768) = SCALE*b1.
// Frag index i = ((nt*4+c)*64 + lane)*8 + j  <->  B[k][n], k=32c+8*(lane>>4)+j,
// n=16*nt+(lane&15)  (mfma_f32_16x16x32_bf16 B-operand layout).
__global__ void prep_kernel(const float* __restrict__ W1, const float* __restrict__ b1,
                            const float* __restrict__ W2, float* __restrict__ ws) {
    int i = blockIdx.x * blockDim.x + threadIdx.x;
    unsigned short* whi = (unsigned short*)ws;
    unsigned short* wlo = whi + 16384;
    if (i < 16384) {
        int j = i & 7, l = (i >> 3) & 63, c = (i >> 9) & 3, nt = (i >> 11) & 7;
        int k = 32 * c + 8 * (l >> 4) + j;
        int n = 16 * nt + (l & 15);
        float v = SCALE * W2[k * WIDTH + n];
        unsigned short hi = f2bf(v);
        whi[i] = hi;
        wlo[i] = f2bf(v - bf2f(hi));
    }
    if (i < 2 * WIDTH) ws[16384 + i] = SCALE * W1[i];
    if (i < WIDTH)     ws[16384 + 256 + i] = SCALE * b1[i];
}

// Build A-fragments (trunc split) for K-chunk cc into AH[4]/AL[4].
// Element j of frag (mt) is A[16*mt+lane15][32*cc+8*kg+j], pairs packed lo/hi.
#define BUILD_A(cc, AH, AL)                                                          \
    {                                                                                \
        _Pragma("unroll")                                                            \
        for (int jq = 0; jq < 2; ++jq) {                                             \
            float4 wxv = *(const float4*)&sWx[32 * (cc) + 8 * kg + 4 * jq];          \
            float4 wyv = *(const float4*)&sWy[32 * (cc) + 8 * kg + 4 * jq];          \
            float4 wbv = *(const float4*)&sWb[32 * (cc) + 8 * kg + 4 * jq];          \
            _Pragma("unroll")                                                        \
            for (int mt = 0; mt < 4; ++mt) {                                         \
                float v0 = sin_rev(fmaf(qx[mt], wxv.x, fmaf(qy[mt], wyv.x, wbv.x))); \
                float v1 = sin_rev(fmaf(qx[mt], wxv.y, fmaf(qy[mt], wyv.y, wbv.y))); \
                float v2 = sin_rev(fmaf(qx[mt], wxv.z, fmaf(qy[mt], wyv.z, wbv.z))); \
                float v3 = sin_rev(fmaf(qx[mt], wxv.w, fmaf(qy[mt], wyv.w, wbv.w))); \
                float r0 = v0 - trunc16f(v0);                                        \
                float r1 = v1 - trunc16f(v1);                                        \
                float r2 = v2 - trunc16f(v2);                                        \
                float r3 = v3 - trunc16f(v3);                                        \
                if (jq == 0) {                                                       \
                    AH[mt].x = pack_hi16(v0, v1); AH[mt].y = pack_hi16(v2, v3);      \
                    AL[mt].x = pack_hi16(r0, r1); AL[mt].y = pack_hi16(r2, r3);      \
                } else {                                                             \
                    AH[mt].z = pack_hi16(v0, v1); AH[mt].w = pack_hi16(v2, v3);      \
                    AL[mt].z = pack_hi16(r0, r1); AL[mt].w = pack_hi16(r2, r3);      \
                }                                                                    \
            }                                                                        \
        }                                                                            \
    }

__launch_bounds__(256, 2)
__global__ void ode_kernel(const float* __restrict__ t,
                           const float2* __restrict__ x0,
                           const float* __restrict__ ws,
                           const float* __restrict__ W3,
                           const float* __restrict__ b2,
                           const float* __restrict__ b3,
                           float2* __restrict__ out) {
    __shared__ unsigned int sBh[8192];                    // W2-hi frags, 32 KB
    __shared__ unsigned int sBl[8192];                    // W2-lo frags, 32 KB
    __shared__ __align__(16) float sWx[WIDTH], sWy[WIDTH], sWb[WIDTH];
    __shared__ float2 sW3[WIDTH];                         // {w3x, w3y}
    __shared__ float  sB2[WIDTH];                         // SCALE*b2

    const int tid = threadIdx.x;
    const int wave = tid >> 6;
    const int lane = tid & 63;
    const int lane15 = lane & 15;
    const int kg = lane >> 4;

    // one-time staging (hi + lo fragment banks)
    {
        const uint4* srch = (const uint4*)ws;
        const uint4* srcl = (const uint4*)(ws + 8192);
        uint4* dsth = (uint4*)sBh;
        uint4* dstl = (uint4*)sBl;
        #pragma unroll
        for (int j = 0; j < 8; ++j) {
            dsth[tid + 256 * j] = srch[tid + 256 * j];
            dstl[tid + 256 * j] = srcl[tid + 256 * j];
        }
    }
    if (tid < WIDTH) {
        sWx[tid] = ws[16384 + tid];
        sWy[tid] = ws[16384 + WIDTH + tid];
        sWb[tid] = ws[16384 + 256 + tid];
        sW3[tid] = make_float2(W3[2 * tid], W3[2 * tid + 1]);
        sB2[tid] = SCALE * b2[tid];
    }
    __syncthreads();   // the ONLY barrier; hot loop is barrier/fence-free

    // Ownership permutation: lane l owns local particle
    //   m(l) = 16*(lane15>>2) + 4*kg + (lane15&3)
    // so the DPP-reduced row sums land at owner lanes: owner's gx slot is
    // 4*(lane15>>2) + (lane15&3) == lane15.
    const int mloc = 16 * (lane15 >> 2) + 4 * kg + (lane15 & 3);
    const int p = blockIdx.x * 256 + wave * 64 + mloc;

    float2 y = x0[p];
    out[p] = y;   // row 0 = x0

    const float b30 = b3[0], b31 = b3[1];

    float tprev = t[0];
    #pragma unroll 1
    for (int step = 0; step < TSTEPS - 1; ++step) {
        const float tnext = t[step + 1];
        const float dt = tnext - tprev;
        tprev = tnext;

        float k1x=0.f,k1y=0.f,k2x=0.f,k2y=0.f,k3x=0.f,k3y=0.f,sx=0.f,sy=0.f;

        #pragma unroll 1
        for (int s = 0; s < 4; ++s) {
            float yinx, yiny;
            if (s == 0)      { yinx = y.x;                                 yiny = y.y; }
            else if (s == 1) { const float c1 = dt * (1.0f / 3.0f);
                               yinx = y.x + c1 * k1x;                       yiny = y.y + c1 * k1y; }
            else if (s == 2) { yinx = y.x + dt * (k2x - (1.0f/3.0f) * k1x); yiny = y.y + dt * (k2y - (1.0f/3.0f) * k1y); }
            else             { yinx = y.x + dt * (k1x - k2x + k3x);         yiny = y.y + dt * (k1y - k2y + k3y); }

            // ---- f(yin) ----
            // Broadcast tile-row coords: row m' = 16*mt + lane15 is owned by
            // lane 16*(lane15>>2) + 4*mt + (lane15&3).
            float qx[4], qy[4];
            {
                const int sbase = 16 * (lane15 >> 2) + (lane15 & 3);
                qx[0] = __shfl(yinx, sbase,      64); qy[0] = __shfl(yiny, sbase,      64);
                qx[1] = __shfl(yinx, sbase + 4,  64); qy[1] = __shfl(yiny, sbase + 4,  64);
                qx[2] = __shfl(yinx, sbase + 8,  64); qy[2] = __shfl(yiny, sbase + 8,  64);
                qx[3] = __shfl(yinx, sbase + 12, 64); qy[3] = __shfl(yiny, sbase + 12, 64);
            }

            // Full-M, full-N GEMM: acc[8nt][4mt] = 128 AGPRs, init = SCALE*b2.
            f32x4 acc[8][4];
            #pragma unroll
            for (int i = 0; i < 8; ++i) {
                const float bb = sB2[16 * i + lane15];
                const f32x4 v4 = (f32x4){bb, bb, bb, bb};
                #pragma unroll
                for (int mt = 0; mt < 4; ++mt) acc[i][mt] = v4;
            }

            // Software-pipelined K-chunks: build A(c+1) overlaps MFMA sweep(c).
            uint4 ah[2][4], al[2][4];
            BUILD_A(0, ah[0], al[0])
            #pragma unroll
            for (int c = 0; c < 4; ++c) {
                if (c < 3) BUILD_A(c + 1, ah[(c + 1) & 1], al[(c + 1) & 1])

                #pragma unroll
                for (int nt = 0; nt < 8; ++nt) {
                    const int fo = (nt * 4 + c) * 256 + lane * 4;
                    uint4 bhU = *(const uint4*)&sBh[fo];
                    uint4 blU = *(const uint4*)&sBl[fo];
                    s16x8 bh = __builtin_bit_cast(s16x8, bhU);
                    s16x8 bl = __builtin_bit_cast(s16x8, blU);
                    #pragma unroll
                    for (int mt = 0; mt < 4; ++mt) {
                        s16x8 ahv = __builtin_bit_cast(s16x8, ah[c & 1][mt]);
                        s16x8 alv = __builtin_bit_cast(s16x8, al[c & 1][mt]);
                        acc[nt][mt] = __builtin_amdgcn_mfma_f32_16x16x32_bf16(ahv, bh, acc[nt][mt], 0, 0, 0);
                        acc[nt][mt] = __builtin_amdgcn_mfma_f32_16x16x32_bf16(alv, bh, acc[nt][mt], 0, 0, 0);
                        acc[nt][mt] = __builtin_amdgcn_mfma_f32_16x16x32_bf16(ahv, bl, acc[nt][mt], 0, 0, 0);
                    }
                }
            }

            // Epilogue: sin + layer-3 column partials (b2 already in acc).
            // C layout: value (nt,mt,r) = row 16*mt+4*kg+r, col 16*nt+lane15.
            float gx[16], gy[16];
            #pragma unroll
            for (int i = 0; i < 16; ++i) { gx[i] = 0.f; gy[i] = 0.f; }
            #pragma unroll
            for (int nt = 0; nt < 8; ++nt) {
                float2 w3v = sW3[16 * nt + lane15];
                #pragma unroll
                for (int mt = 0; mt < 4; ++mt) {
                    #pragma unroll
                    for (int r = 0; r < 4; ++r) {
                        float sn = sin_rev(acc[nt][mt][r]);
                        gx[4*mt+r] = fmaf(sn, w3v.x, gx[4*mt+r]);
                        gy[4*mt+r] = fmaf(sn, w3v.y, gy[4*mt+r]);
                    }
                }
            }
            // 16-lane n-reduction (DPP, no LDS); owner slot is lane15.
            #pragma unroll
            for (int i = 0; i < 16; ++i) { gx[i] = row_sum16(gx[i]); gy[i] = row_sum16(gy[i]); }
            const float fx = b30 + sel16(gx, lane15);
            const float fy = b31 + sel16(gy, lane15);
            // ---- end f ----

            if (s == 0)      { k1x = fx; k1y = fy; sx = fx;        sy = fy; }
            else if (s == 1) { k2x = fx; k2y = fy; sx += 3.f * fx; sy += 3.f * fy; }
            else if (s == 2) { k3x = fx; k3y = fy; sx += 3.f * fx; sy += 3.f * fy; }
            else             {                     sx += fx;       sy += fy; }
        }

        const float cc = dt * 0.125f;
        y.x += sx * cc;
        y.y += sy * cc;
        out[(size_t)(step + 1) * NPART + p] = y;
    }
}

extern "C" void kernel_launch(void* const* d_in, const int* in_sizes, int n_in,
                              void* d_out, int out_size, void* d_ws, size_t ws_size,
                              hipStream_t stream) {
    const float*  t  = (const float*)d_in[0];
    const float2* x0 = (const float2*)d_in[1];
    const float*  W1 = (const float*)d_in[2];
    const float*  b1 = (const float*)d_in[3];
    const float*  W2 = (const float*)d_in[4];
    const float*  b2 = (const float*)d_in[5];
    const float*  W3 = (const float*)d_in[6];
    const float*  b3 = (const float*)d_in[7];
    float* ws = (float*)d_ws;
    float2* out = (float2*)d_out;

    prep_kernel<<<64, 256, 0, stream>>>(W1, b1, W2, ws);
    ode_kernel<<<NPART / 256, 256, 0, stream>>>(t, x0, ws, W3, b2, b3, out);
}

// Round 6
// 9494.400 us; speedup vs baseline: 3.2481x; 3.2481x over previous
//
#include <hip/hip_runtime.h>

// NeuralODE SIREN (2->128->128->2, sin, w0=44), RK4 3/8-rule, 100 steps.
// Round 8: revert round-7's software pipeline (full c-unroll + double-buffered
// A-frags overflowed regalloc -> 91GB FETCH / 15GB WRITE of scratch traffic,
// 2.6x regression). Keep round-6's zero-spill structure (#pragma unroll 1
// c-loop, single A-frag buffer) and keep the two VALU cuts that round 7
// hardware-validated for accuracy (absmax unchanged at 0.015625):
//  - fract DROPPED: weights prescaled to revolutions, |z| <= ~55 << v_sin's
//    +-256 valid domain. -256 VALU inst/f-eval, shorter sin chain.
//  - A hi/lo via TRUNCATION split + v_perm packing: ah = top16 bits (pair
//    packed by ONE v_perm), al = top16 of exact residual (ONE v_perm).
//  - NEW: s_setprio(1) around the MFMA sweep -- waves here are independent
//    (no hot-loop barriers), the T5-positive regime (attn-like, m191).
// Spill canaries: WRITE_SIZE must be ~2.13e5 KB, FETCH ~2e3 KB.

#define W0F    44.0f
#define INV2PI 0.15915494309189535f
#define SCALE  (W0F * INV2PI)
#define WIDTH  128
#define NPART  262144
#define TSTEPS 101

typedef short s16x8 __attribute__((ext_vector_type(8)));
typedef float f32x4 __attribute__((ext_vector_type(4)));

__device__ __forceinline__ float sin_rev(float z) {
    // sin(2*pi*z) via v_sin_f32 (revolutions). Valid domain +-256 rev;
    // |z| <= ~55 here (|x|<=7, |W1|<=0.5, SCALE=7.005). No fract needed.
    return __builtin_amdgcn_sinf(z);
}
__device__ __forceinline__ unsigned short f2bf(float x) {   // RNE f32->bf16
    __bf16 b = (__bf16)x;
    return __builtin_bit_cast(unsigned short, b);
}
__device__ __forceinline__ float bf2f(unsigned short u) {   // exact bf16->f32
    unsigned int v = ((unsigned int)u) << 16;
    return __builtin_bit_cast(float, v);
}
__device__ __forceinline__ float trunc16f(float v) {        // clear low 16 mantissa bits
    return __builtin_bit_cast(float, __builtin_bit_cast(unsigned int, v) & 0xffff0000u);
}
__device__ __forceinline__ unsigned int pack_hi16(float vlo, float vhi) {
    // {top16(vhi) : top16(vlo)} in one v_perm_b32
    return __builtin_amdgcn_perm(__builtin_bit_cast(unsigned int, vhi),
                                 __builtin_bit_cast(unsigned int, vlo),
                                 0x07060302u);
}

// ---- 16-lane (DPP row) all-lanes sum via circulant row_ror adds ----
#define ROR_ADD(x, ctrl) ((x) + __builtin_bit_cast(float, \
    __builtin_amdgcn_update_dpp(0, __builtin_bit_cast(int, (x)), (ctrl), 0xF, 0xF, false)))
__device__ __forceinline__ float row_sum16(float x) {
    x = ROR_ADD(x, 0x128);   // row_ror:8
    x = ROR_ADD(x, 0x124);   // row_ror:4
    x = ROR_ADD(x, 0x122);   // row_ror:2
    x = ROR_ADD(x, 0x121);   // row_ror:1
    return x;                // every lane holds the 16-lane sum
}

// 16-way register select (15 v_cndmask), idx = per-lane 0..15
__device__ __forceinline__ float sel16(const float g[16], int idx) {
    float a[8], b[4], c[2];
    #pragma unroll
    for (int i = 0; i < 8; ++i) a[i] = (idx & 8) ? g[i + 8] : g[i];
    #pragma unroll
    for (int i = 0; i < 4; ++i) b[i] = (idx & 4) ? a[i + 4] : a[i];
    #pragma unroll
    for (int i = 0; i < 2; ++i) c[i] = (idx & 2) ? b[i + 2] : b[i];
    return (idx & 1) ? c[1] : c[0];
}

// ws layout: shorts [0,16384) = W2-hi B-frags; shorts [16384,32768) = W2-lo
// B-frags; floats [16384,16640) = SCALE*W1; floats [16640,16768) = SCALE*b1.
// Frag index i = ((nt*4+c)*64 + lane)*8 + j  <->  B[k][n], k=32c+8*(lane>>4)+j,
// n=16*nt+(lane&15)  (mfma_f32_16x16x32_bf16 B-operand layout).
__global__ void prep_kernel(const float* __restrict__ W1, const float* __restrict__ b1,
                            const float* __restrict__ W2, float* __restrict__ ws) {
    int i = blockIdx.x * blockDim.x + threadIdx.x;
    unsigned short* whi = (unsigned short*)ws;
    unsigned short* wlo = whi + 16384;
    if (i < 16384) {
        int j = i & 7, l = (i >> 3) & 63, c = (i >> 9) & 3, nt = (i >> 11) & 7;
        int k = 32 * c + 8 * (l >> 4) + j;
        int n = 16 * nt + (l & 15);
        float v = SCALE * W2[k * WIDTH + n];
        unsigned short hi = f2bf(v);
        whi[i] = hi;
        wlo[i] = f2bf(v - bf2f(hi));
    }
    if (i < 2 * WIDTH) ws[16384 + i] = SCALE * W1[i];
    if (i < WIDTH)     ws[16384 + 256 + i] = SCALE * b1[i];
}

__launch_bounds__(256, 2)
__global__ void ode_kernel(const float* __restrict__ t,
                           const float2* __restrict__ x0,
                           const float* __restrict__ ws,
                           const float* __restrict__ W3,
                           const float* __restrict__ b2,
                           const float* __restrict__ b3,
                           float2* __restrict__ out) {
    __shared__ unsigned int sBh[8192];                    // W2-hi frags, 32 KB
    __shared__ unsigned int sBl[8192];                    // W2-lo frags, 32 KB
    __shared__ __align__(16) float sWx[WIDTH], sWy[WIDTH], sWb[WIDTH];
    __shared__ float2 sW3[WIDTH];                         // {w3x, w3y}
    __shared__ float  sB2[WIDTH];                         // SCALE*b2

    const int tid = threadIdx.x;
    const int wave = tid >> 6;
    const int lane = tid & 63;
    const int lane15 = lane & 15;
    const int kg = lane >> 4;

    // one-time staging (hi + lo fragment banks)
    {
        const uint4* srch = (const uint4*)ws;
        const uint4* srcl = (const uint4*)(ws + 8192);
        uint4* dsth = (uint4*)sBh;
        uint4* dstl = (uint4*)sBl;
        #pragma unroll
        for (int j = 0; j < 8; ++j) {
            dsth[tid + 256 * j] = srch[tid + 256 * j];
            dstl[tid + 256 * j] = srcl[tid + 256 * j];
        }
    }
    if (tid < WIDTH) {
        sWx[tid] = ws[16384 + tid];
        sWy[tid] = ws[16384 + WIDTH + tid];
        sWb[tid] = ws[16384 + 256 + tid];
        sW3[tid] = make_float2(W3[2 * tid], W3[2 * tid + 1]);
        sB2[tid] = SCALE * b2[tid];
    }
    __syncthreads();   // the ONLY barrier; hot loop is barrier/fence-free

    // Ownership permutation: lane l owns local particle
    //   m(l) = 16*(lane15>>2) + 4*kg + (lane15&3)
    // so the DPP-reduced row sums land at owner lanes: owner's gx slot is
    // 4*(lane15>>2) + (lane15&3) == lane15.
    const int mloc = 16 * (lane15 >> 2) + 4 * kg + (lane15 & 3);
    const int p = blockIdx.x * 256 + wave * 64 + mloc;

    float2 y = x0[p];
    out[p] = y;   // row 0 = x0

    const float b30 = b3[0], b31 = b3[1];

    float tprev = t[0];
    #pragma unroll 1
    for (int step = 0; step < TSTEPS - 1; ++step) {
        const float tnext = t[step + 1];
        const float dt = tnext - tprev;
        tprev = tnext;

        float k1x=0.f,k1y=0.f,k2x=0.f,k2y=0.f,k3x=0.f,k3y=0.f,sx=0.f,sy=0.f;

        #pragma unroll 1
        for (int s = 0; s < 4; ++s) {
            float yinx, yiny;
            if (s == 0)      { yinx = y.x;                                 yiny = y.y; }
            else if (s == 1) { const float c1 = dt * (1.0f / 3.0f);
                               yinx = y.x + c1 * k1x;                       yiny = y.y + c1 * k1y; }
            else if (s == 2) { yinx = y.x + dt * (k2x - (1.0f/3.0f) * k1x); yiny = y.y + dt * (k2y - (1.0f/3.0f) * k1y); }
            else             { yinx = y.x + dt * (k1x - k2x + k3x);         yiny = y.y + dt * (k1y - k2y + k3y); }

            // ---- f(yin) ----
            // Broadcast tile-row coords: row m' = 16*mt + lane15 is owned by
            // lane 16*(lane15>>2) + 4*mt + (lane15&3).
            float qx[4], qy[4];
            {
                const int sbase = 16 * (lane15 >> 2) + (lane15 & 3);
                qx[0] = __shfl(yinx, sbase,      64); qy[0] = __shfl(yiny, sbase,      64);
                qx[1] = __shfl(yinx, sbase + 4,  64); qy[1] = __shfl(yiny, sbase + 4,  64);
                qx[2] = __shfl(yinx, sbase + 8,  64); qy[2] = __shfl(yiny, sbase + 8,  64);
                qx[3] = __shfl(yinx, sbase + 12, 64); qy[3] = __shfl(yiny, sbase + 12, 64);
            }

            // Full-M, full-N GEMM: acc[8nt][4mt] = 128 AGPRs, init = SCALE*b2.
            f32x4 acc[8][4];
            #pragma unroll
            for (int i = 0; i < 8; ++i) {
                const float bb = sB2[16 * i + lane15];
                const f32x4 v4 = (f32x4){bb, bb, bb, bb};
                #pragma unroll
                for (int mt = 0; mt < 4; ++mt) acc[i][mt] = v4;
            }

            #pragma unroll 1
            for (int c = 0; c < 4; ++c) {
                // Build A-fragments in-layout as aligned quads (trunc split +
                // v_perm packing): element j of frag (mt) is
                // A[16*mt+lane15][32*c+8*kg+j], pairs packed lo/hi.
                uint4 ah[4], al[4];
                #pragma unroll
                for (int jq = 0; jq < 2; ++jq) {
                    float4 wxv = *(const float4*)&sWx[32 * c + 8 * kg + 4 * jq];
                    float4 wyv = *(const float4*)&sWy[32 * c + 8 * kg + 4 * jq];
                    float4 wbv = *(const float4*)&sWb[32 * c + 8 * kg + 4 * jq];
                    #pragma unroll
                    for (int mt = 0; mt < 4; ++mt) {
                        float v0 = sin_rev(fmaf(qx[mt], wxv.x, fmaf(qy[mt], wyv.x, wbv.x)));
                        float v1 = sin_rev(fmaf(qx[mt], wxv.y, fmaf(qy[mt], wyv.y, wbv.y)));
                        float v2 = sin_rev(fmaf(qx[mt], wxv.z, fmaf(qy[mt], wyv.z, wbv.z)));
                        float v3 = sin_rev(fmaf(qx[mt], wxv.w, fmaf(qy[mt], wyv.w, wbv.w)));
                        float r0 = v0 - trunc16f(v0);
                        float r1 = v1 - trunc16f(v1);
                        float r2 = v2 - trunc16f(v2);
                        float r3 = v3 - trunc16f(v3);
                        if (jq == 0) {
                            ah[mt].x = pack_hi16(v0, v1); ah[mt].y = pack_hi16(v2, v3);
                            al[mt].x = pack_hi16(r0, r1); al[mt].y = pack_hi16(r2, r3);
                        } else {
                            ah[mt].z = pack_hi16(v0, v1); ah[mt].w = pack_hi16(v2, v3);
                            al[mt].z = pack_hi16(r0, r1); al[mt].w = pack_hi16(r2, r3);
                        }
                    }
                }

                // Full-N sweep, B from LDS only (hi and lo banks). MFMA burst
                // wrapped in setprio(1): waves are unsynced, so the CU
                // scheduler can favor the MFMA-issuing wave (T5 regime).
                __builtin_amdgcn_s_setprio(1);
                #pragma unroll
                for (int nt = 0; nt < 8; ++nt) {
                    const int fo = (nt * 4 + c) * 256 + lane * 4;
                    uint4 bhU = *(const uint4*)&sBh[fo];
                    uint4 blU = *(const uint4*)&sBl[fo];
                    s16x8 bh = __builtin_bit_cast(s16x8, bhU);
                    s16x8 bl = __builtin_bit_cast(s16x8, blU);
                    #pragma unroll
                    for (int mt = 0; mt < 4; ++mt) {
                        s16x8 ahv = __builtin_bit_cast(s16x8, ah[mt]);
                        s16x8 alv = __builtin_bit_cast(s16x8, al[mt]);
                        acc[nt][mt] = __builtin_amdgcn_mfma_f32_16x16x32_bf16(ahv, bh, acc[nt][mt], 0, 0, 0);
                        acc[nt][mt] = __builtin_amdgcn_mfma_f32_16x16x32_bf16(alv, bh, acc[nt][mt], 0, 0, 0);
                        acc[nt][mt] = __builtin_amdgcn_mfma_f32_16x16x32_bf16(ahv, bl, acc[nt][mt], 0, 0, 0);
                    }
                }
                __builtin_amdgcn_s_setprio(0);
            }

            // Epilogue: sin + layer-3 column partials (b2 already in acc).
            // C layout: value (nt,mt,r) = row 16*mt+4*kg+r, col 16*nt+lane15.
            float gx[16], gy[16];
            #pragma unroll
            for (int i = 0; i < 16; ++i) { gx[i] = 0.f; gy[i] = 0.f; }
            #pragma unroll
            for (int nt = 0; nt < 8; ++nt) {
                float2 w3v = sW3[16 * nt + lane15];
                #pragma unroll
                for (int mt = 0; mt < 4; ++mt) {
                    #pragma unroll
                    for (int r = 0; r < 4; ++r) {
                        float sn = sin_rev(acc[nt][mt][r]);
                        gx[4*mt+r] = fmaf(sn, w3v.x, gx[4*mt+r]);
                        gy[4*mt+r] = fmaf(sn, w3v.y, gy[4*mt+r]);
                    }
                }
            }
            // 16-lane n-reduction (DPP, no LDS); owner slot is lane15.
            #pragma unroll
            for (int i = 0; i < 16; ++i) { gx[i] = row_sum16(gx[i]); gy[i] = row_sum16(gy[i]); }
            const float fx = b30 + sel16(gx, lane15);
            const float fy = b31 + sel16(gy, lane15);
            // ---- end f ----

            if (s == 0)      { k1x = fx; k1y = fy; sx = fx;        sy = fy; }
            else if (s == 1) { k2x = fx; k2y = fy; sx += 3.f * fx; sy += 3.f * fy; }
            else if (s == 2) { k3x = fx; k3y = fy; sx += 3.f * fx; sy += 3.f * fy; }
            else             {                     sx += fx;       sy += fy; }
        }

        const float cc = dt * 0.125f;
        y.x += sx * cc;
        y.y += sy * cc;
        out[(size_t)(step + 1) * NPART + p] = y;
    }
}

extern "C" void kernel_launch(void* const* d_in, const int* in_sizes, int n_in,
                              void* d_out, int out_size, void* d_ws, size_t ws_size,
                              hipStream_t stream) {
    const float*  t  = (const float*)d_in[0];
    const float2* x0 = (const float2*)d_in[1];
    const float*  W1 = (const float*)d_in[2];
    const float*  b1 = (const float*)d_in[3];
    const float*  W2 = (const float*)d_in[4];
    const float*  b2 = (const float*)d_in[5];
    const float*  W3 = (const float*)d_in[6];
    const float*  b3 = (const float*)d_in[7];
    float* ws = (float*)d_ws;
    float2* out = (float2*)d_out;

    prep_kernel<<<64, 256, 0, stream>>>(W1, b1, W2, ws);
    ode_kernel<<<NPART / 256, 256, 0, stream>>>(t, x0, ws, W3, b2, b3, out);
}